// Round 7
// baseline (55.601 us; speedup 1.0000x reference)
//
#include <hip/hip_runtime.h>
#include <hip/hip_fp16.h>

#define INPUT_SIZE 128
#define NUM_REL 16

typedef int   i32x4 __attribute__((ext_vector_type(4)));
typedef float f32x4 __attribute__((ext_vector_type(4)));

// ---------------------------------------------------------------------------
// Kernel 1: per-node logit tables, SPLIT fp16 output (unchanged since R5).
//   Ls[n][r] = x[n] . att_weight[0:128, r]      (r = 0..15)
//   Ld[n][r] = x[n] . att_weight[128:256, r]
// 256 threads = 128 nodes/block, 4 nodes x 4 rels per thread. w staged in LDS
// repacked swc[k][32]; ds_read_b128 per 4 rels, conflict-free.
// ---------------------------------------------------------------------------
__global__ __launch_bounds__(256) void node_logits_kernel(
    const float* __restrict__ x,
    const float* __restrict__ w,      // (256,16) row-major
    __half* __restrict__ Ls,          // (num_nodes, 16) fp16
    __half* __restrict__ Ld,          // (num_nodes, 16) fp16
    int num_nodes)
{
    __shared__ float swc[128 * 32];   // swc[k*32 + r], 16 KB

    const int tid = threadIdx.x;

    #pragma unroll
    for (int i = 0; i < 16; ++i) {
        const int idx = i * 256 + tid;         // 0..4095
        const int k = idx >> 5, r = idx & 31;
        swc[idx] = (r < 16) ? w[k * NUM_REL + r]
                            : w[(INPUT_SIZE + k) * NUM_REL + (r - 16)];
    }
    __syncthreads();

    const int ng = tid >> 3;                   // node group 0..31
    const int rg = tid & 7;                    // rel group  0..7 (0-3 src, 4-7 dst)
    const int node0 = blockIdx.x * 128 + ng * 4;
    const int r0 = rg * 4;

    const f32x4* xr[4];
    bool valid[4];
    #pragma unroll
    for (int n = 0; n < 4; ++n) {
        const int nn = node0 + n;
        valid[n] = (nn < num_nodes);
        xr[n] = (const f32x4*)(x + (size_t)(valid[n] ? nn : 0) * INPUT_SIZE);
    }

    float acc[4][4] = {};

    #pragma unroll 4
    for (int ks = 0; ks < 32; ++ks) {          // 4 k's per step
        f32x4 xv[4], wv[4];
        #pragma unroll
        for (int n = 0; n < 4; ++n) xv[n] = xr[n][ks];
        #pragma unroll
        for (int kk = 0; kk < 4; ++kk)
            wv[kk] = *(const f32x4*)&swc[(ks * 4 + kk) * 32 + r0];

        #pragma unroll
        for (int n = 0; n < 4; ++n) {
            #pragma unroll
            for (int c = 0; c < 4; ++c) {
                acc[n][0] += xv[n][c] * wv[c][0];
                acc[n][1] += xv[n][c] * wv[c][1];
                acc[n][2] += xv[n][c] * wv[c][2];
                acc[n][3] += xv[n][c] * wv[c][3];
            }
        }
    }

    __half* base = (rg < 4) ? Ls : Ld;
    const int rr = (rg & 3) * 4;
    #pragma unroll
    for (int n = 0; n < 4; ++n) {
        if (!valid[n]) continue;
        union { __half2 h2[2]; uint2 u; } pk;
        pk.h2[0] = __floats2half2_rn(acc[n][0], acc[n][1]);
        pk.h2[1] = __floats2half2_rn(acc[n][2], acc[n][3]);
        *(uint2*)(base + (size_t)(node0 + n) * NUM_REL + rr) = pk.u;   // 8B aligned
    }
}

// ---------------------------------------------------------------------------
// Src pass, node range [lo,hi): partial[e] = Ls[s[e]][t[e]] for s in range.
// Hot gather slab = (hi-lo)*32B ~ 0.8 MB -> L2-resident per XCD.
// Out-of-range lanes skip (their edge is handled by the other pass).
// ---------------------------------------------------------------------------
__global__ __launch_bounds__(256) void edge_src_pass(
    const int* __restrict__ ei,       // (2, E) int32 (src half used)
    const int* __restrict__ et,       // (E,) int32
    const __half* __restrict__ Ls,    // (N, 16)
    __half* __restrict__ partial,     // (E,) fp16
    int num_edges, int lo, int hi)
{
    const int i = blockIdx.x * blockDim.x + threadIdx.x;   // quad index
    const int e0 = i * 4;
    if (e0 >= num_edges) return;

    const i32x4 s4 = ((const i32x4*)ei)[i];
    const i32x4 t4 = ((const i32x4*)et)[i];

    #pragma unroll
    for (int j = 0; j < 4; ++j) {
        const int s = s4[j];
        if (s >= lo && s < hi)
            partial[e0 + j] = Ls[(size_t)s * NUM_REL + t4[j]];
    }
}

// ---------------------------------------------------------------------------
// Dst pass, node range [lo,hi): out[e] = clamp(sigmoid(partial[e] + Ld[d][t]))
// for d in range. Hot slab 0.8 MB -> L2-resident.
// ---------------------------------------------------------------------------
__global__ __launch_bounds__(256) void edge_dst_pass(
    const int* __restrict__ ei,       // (2, E) int32 (dst half used)
    const int* __restrict__ et,       // (E,) int32
    const __half* __restrict__ Ld,    // (N, 16)
    const __half* __restrict__ partial,
    float* __restrict__ out,
    int num_edges, int lo, int hi)
{
    const int i = blockIdx.x * blockDim.x + threadIdx.x;   // quad index
    const int e0 = i * 4;
    if (e0 >= num_edges) return;

    const i32x4 d4 = ((const i32x4*)(ei + num_edges))[i];
    const i32x4 t4 = ((const i32x4*)et)[i];

    #pragma unroll
    for (int j = 0; j < 4; ++j) {
        const int d = d4[j];
        if (d >= lo && d < hi) {
            const float sc = __half2float(partial[e0 + j])
                           + __half2float(Ld[(size_t)d * NUM_REL + t4[j]]);
            const float att = 1.f / (1.f + __expf(-sc));
            out[e0 + j] = fminf(fmaxf(att, 1e-5f), 0.99999f);
        }
    }
}

// Fallback: direct per-edge dot product in f32 (no workspace).
__global__ void edge_direct_kernel(const float* __restrict__ x,
                                   const float* __restrict__ w,
                                   const int* __restrict__ ei,
                                   const int* __restrict__ et,
                                   float* __restrict__ out,
                                   int num_edges) {
    const int e = blockIdx.x * blockDim.x + threadIdx.x;
    if (e >= num_edges) return;
    const int s = ei[e];
    const int d = ei[num_edges + e];
    const int t = et[e];
    const float* xs = x + (size_t)s * INPUT_SIZE;
    const float* xd = x + (size_t)d * INPUT_SIZE;
    float acc = 0.f;
    #pragma unroll 4
    for (int k = 0; k < INPUT_SIZE; ++k)
        acc += xs[k] * w[k * NUM_REL + t] + xd[k] * w[(INPUT_SIZE + k) * NUM_REL + t];
    const float att = 1.f / (1.f + __expf(-acc));
    out[e] = fminf(fmaxf(att, 1e-5f), 0.99999f);
}

extern "C" void kernel_launch(void* const* d_in, const int* in_sizes, int n_in,
                              void* d_out, int out_size, void* d_ws, size_t ws_size,
                              hipStream_t stream) {
    const float* x  = (const float*)d_in[0];   // (50000, 128) f32
    const float* w  = (const float*)d_in[1];   // (256, 16) f32
    const int*   ei = (const int*)d_in[2];     // (2, E) int32
    const int*   et = (const int*)d_in[3];     // (E,) int32
    float* out = (float*)d_out;

    const int num_nodes = in_sizes[0] / INPUT_SIZE;
    const int num_edges = in_sizes[3];

    const size_t tbl_bytes = (size_t)num_nodes * NUM_REL * sizeof(__half); // 1.6 MB
    const size_t par_bytes = (size_t)num_edges * sizeof(__half);           // 3.2 MB
    const size_t ws_needed = 2 * tbl_bytes + par_bytes;

    if (ws_size >= ws_needed && (num_edges & 3) == 0) {
        __half* Ls      = (__half*)d_ws;
        __half* Ld      = (__half*)((char*)d_ws + tbl_bytes);
        __half* partial = (__half*)((char*)d_ws + 2 * tbl_bytes);

        const int blocks1 = (num_nodes + 127) / 128;
        node_logits_kernel<<<blocks1, 256, 0, stream>>>(x, w, Ls, Ld, num_nodes);

        const int quads   = num_edges / 4;
        const int blocks2 = (quads + 255) / 256;
        const int mid     = num_nodes / 2;

        // All src passes first (partial must be complete before any dst pass,
        // since an edge's s-range and d-range are independent).
        edge_src_pass<<<blocks2, 256, 0, stream>>>(ei, et, Ls, partial,
                                                   num_edges, 0, mid);
        edge_src_pass<<<blocks2, 256, 0, stream>>>(ei, et, Ls, partial,
                                                   num_edges, mid, num_nodes);
        edge_dst_pass<<<blocks2, 256, 0, stream>>>(ei, et, Ld, partial, out,
                                                   num_edges, 0, mid);
        edge_dst_pass<<<blocks2, 256, 0, stream>>>(ei, et, Ld, partial, out,
                                                   num_edges, mid, num_nodes);
    } else {
        const int blocks = (num_edges + 255) / 256;
        edge_direct_kernel<<<blocks, 256, 0, stream>>>(x, w, ei, et, out, num_edges);
    }
}

// Round 8
// 55.239 us; speedup vs baseline: 1.0066x; 1.0066x over previous
//
#include <hip/hip_runtime.h>
#include <hip/hip_fp16.h>

#define INPUT_SIZE 128
#define NUM_REL 16

typedef int   i32x4 __attribute__((ext_vector_type(4)));
typedef float f32x4 __attribute__((ext_vector_type(4)));

// ---------------------------------------------------------------------------
// Kernel 1: per-node logit table, f32 output, R1 layout: L[n][32] with
//   L[n][r]    = x[n] . att_weight[0:128, r]      (r = 0..15, src half)
//   L[n][16+r] = x[n] . att_weight[128:256, r]    (dst half)
// 256 threads = 128 nodes/block, 4 nodes x 4 rels per thread (fast k1 of
// R2+). w staged in LDS repacked swc[k][32]; ds_read_b128 per 4 rels,
// conflict-free.
// ---------------------------------------------------------------------------
__global__ __launch_bounds__(256) void node_logits_kernel(
    const float* __restrict__ x,
    const float* __restrict__ w,      // (256,16) row-major
    float* __restrict__ L,            // (num_nodes, 32) f32
    int num_nodes)
{
    __shared__ float swc[128 * 32];   // swc[k*32 + r], 16 KB

    const int tid = threadIdx.x;

    // Stage + repack weights: swc[k][r] = r<16 ? w[k][r] : w[128+k][r-16]
    #pragma unroll
    for (int i = 0; i < 16; ++i) {
        const int idx = i * 256 + tid;         // 0..4095
        const int k = idx >> 5, r = idx & 31;
        swc[idx] = (r < 16) ? w[k * NUM_REL + r]
                            : w[(INPUT_SIZE + k) * NUM_REL + (r - 16)];
    }
    __syncthreads();

    const int ng = tid >> 3;                   // node group 0..31
    const int rg = tid & 7;                    // rel group  0..7 (0-3 src, 4-7 dst)
    const int node0 = blockIdx.x * 128 + ng * 4;
    const int r0 = rg * 4;

    const f32x4* xr[4];
    bool valid[4];
    #pragma unroll
    for (int n = 0; n < 4; ++n) {
        const int nn = node0 + n;
        valid[n] = (nn < num_nodes);
        xr[n] = (const f32x4*)(x + (size_t)(valid[n] ? nn : 0) * INPUT_SIZE);
    }

    float acc[4][4] = {};

    #pragma unroll 4
    for (int ks = 0; ks < 32; ++ks) {          // 4 k's per step
        f32x4 xv[4], wv[4];
        #pragma unroll
        for (int n = 0; n < 4; ++n) xv[n] = xr[n][ks];
        #pragma unroll
        for (int kk = 0; kk < 4; ++kk)
            wv[kk] = *(const f32x4*)&swc[(ks * 4 + kk) * 32 + r0];

        #pragma unroll
        for (int n = 0; n < 4; ++n) {
            #pragma unroll
            for (int c = 0; c < 4; ++c) {
                acc[n][0] += xv[n][c] * wv[c][0];
                acc[n][1] += xv[n][c] * wv[c][1];
                acc[n][2] += xv[n][c] * wv[c][2];
                acc[n][3] += xv[n][c] * wv[c][3];
            }
        }
    }

    // R1 layout: src rels at [0:16), dst rels at [16:32) of the same row.
    const int col0 = ((rg < 4) ? 0 : 16) + (rg & 3) * 4;
    #pragma unroll
    for (int n = 0; n < 4; ++n) {
        if (!valid[n]) continue;
        f32x4 v = { acc[n][0], acc[n][1], acc[n][2], acc[n][3] };
        *(f32x4*)(L + (size_t)(node0 + n) * 32 + col0) = v;   // 16B store
    }
}

// ---------------------------------------------------------------------------
// Kernel 2: R1's edge kernel VERBATIM. 4 edges/thread, f32 dword gathers.
// (Replication probe: R1's k2 may have been ~22-27 us vs ~36 for all
// fp16-table variants since; isolate the table-dtype/shape variable.)
// ---------------------------------------------------------------------------
__global__ __launch_bounds__(256) void edge_score_kernel(
    const int* __restrict__ ei,   // (2, E) int32
    const int* __restrict__ et,   // (E,) int32
    const float* __restrict__ L,  // (N, 32) f32
    float* __restrict__ out,
    int num_edges)
{
    const int i = blockIdx.x * blockDim.x + threadIdx.x;  // quad index
    const int e0 = i * 4;
    if (e0 >= num_edges) return;

    const i32x4 s4 = ((const i32x4*)ei)[i];
    const i32x4 d4 = ((const i32x4*)(ei + num_edges))[i];
    const i32x4 t4 = ((const i32x4*)et)[i];

    float r[4];
    #pragma unroll
    for (int j = 0; j < 4; ++j) {
        const float sc = L[(size_t)s4[j] * 32 + t4[j]]
                       + L[(size_t)d4[j] * 32 + 16 + t4[j]];
        const float att = 1.f / (1.f + __expf(-sc));
        r[j] = fminf(fmaxf(att, 1e-5f), 0.99999f);
    }
    f32x4 v = { r[0], r[1], r[2], r[3] };
    ((f32x4*)out)[i] = v;
}

// Fallback: direct per-edge dot product in f32 (no workspace).
__global__ void edge_direct_kernel(const float* __restrict__ x,
                                   const float* __restrict__ w,
                                   const int* __restrict__ ei,
                                   const int* __restrict__ et,
                                   float* __restrict__ out,
                                   int num_edges) {
    const int e = blockIdx.x * blockDim.x + threadIdx.x;
    if (e >= num_edges) return;
    const int s = ei[e];
    const int d = ei[num_edges + e];
    const int t = et[e];
    const float* xs = x + (size_t)s * INPUT_SIZE;
    const float* xd = x + (size_t)d * INPUT_SIZE;
    float acc = 0.f;
    #pragma unroll 4
    for (int k = 0; k < INPUT_SIZE; ++k)
        acc += xs[k] * w[k * NUM_REL + t] + xd[k] * w[(INPUT_SIZE + k) * NUM_REL + t];
    const float att = 1.f / (1.f + __expf(-acc));
    out[e] = fminf(fmaxf(att, 1e-5f), 0.99999f);
}

extern "C" void kernel_launch(void* const* d_in, const int* in_sizes, int n_in,
                              void* d_out, int out_size, void* d_ws, size_t ws_size,
                              hipStream_t stream) {
    const float* x  = (const float*)d_in[0];   // (50000, 128) f32
    const float* w  = (const float*)d_in[1];   // (256, 16) f32
    const int*   ei = (const int*)d_in[2];     // (2, E) int32
    const int*   et = (const int*)d_in[3];     // (E,) int32
    float* out = (float*)d_out;

    const int num_nodes = in_sizes[0] / INPUT_SIZE;
    const int num_edges = in_sizes[3];

    const size_t ws_needed = (size_t)num_nodes * 32 * sizeof(float);  // 6.4 MB

    if (ws_size >= ws_needed && (num_edges & 3) == 0) {
        float* L = (float*)d_ws;

        const int blocks1 = (num_nodes + 127) / 128;
        node_logits_kernel<<<blocks1, 256, 0, stream>>>(x, w, L, num_nodes);

        const int quads   = num_edges / 4;
        const int blocks2 = (quads + 255) / 256;
        edge_score_kernel<<<blocks2, 256, 0, stream>>>(ei, et, L, out, num_edges);
    } else {
        const int blocks = (num_edges + 255) / 256;
        edge_direct_kernel<<<blocks, 256, 0, stream>>>(x, w, ei, et, out, num_edges);
    }
}

// Round 9
// 45.332 us; speedup vs baseline: 1.2265x; 1.2185x over previous
//
#include <hip/hip_runtime.h>
#include <hip/hip_fp16.h>

#define INPUT_SIZE 128
#define NUM_REL 16

typedef int   i32x4 __attribute__((ext_vector_type(4)));
typedef float f32x4 __attribute__((ext_vector_type(4)));

// ---------------------------------------------------------------------------
// Kernel 1: per-node logits, RELATION-MAJOR fp16 table.
//   LR[r][n]      = x[n] . att_weight[0:128, r]     (r = 0..15, src slabs)
//   LR[16+r][n]   = x[n] . att_weight[128:256, r]   (dst slabs)
// Slab stride Npad (node-padded). 256 thr = 128 nodes/block, 4 nodes x 4 rels
// per thread; per-thread transpose packs 4 node-halfs per rel -> 8B stores.
// ---------------------------------------------------------------------------
__global__ __launch_bounds__(256) void node_logits_rm(
    const float* __restrict__ x,
    const float* __restrict__ w,      // (256,16) row-major
    __half* __restrict__ LR,          // (32, Npad) fp16, relation-major
    int Npad, int num_nodes)
{
    __shared__ float swc[128 * 32];   // swc[k*32 + r], 16 KB

    const int tid = threadIdx.x;

    // Stage + repack weights: swc[k][r] = r<16 ? w[k][r] : w[128+k][r-16]
    #pragma unroll
    for (int i = 0; i < 16; ++i) {
        const int idx = i * 256 + tid;         // 0..4095
        const int k = idx >> 5, r = idx & 31;
        swc[idx] = (r < 16) ? w[k * NUM_REL + r]
                            : w[(INPUT_SIZE + k) * NUM_REL + (r - 16)];
    }
    __syncthreads();

    const int ng = tid >> 3;                   // node group 0..31
    const int rg = tid & 7;                    // rel group  0..7
    const int node0 = blockIdx.x * 128 + ng * 4;
    const int r0 = rg * 4;                     // 0..28: covers all 32 slabs

    const f32x4* xr[4];
    bool valid[4];
    #pragma unroll
    for (int n = 0; n < 4; ++n) {
        const int nn = node0 + n;
        valid[n] = (nn < num_nodes);
        xr[n] = (const f32x4*)(x + (size_t)(valid[n] ? nn : 0) * INPUT_SIZE);
    }

    float acc[4][4] = {};                      // [node][rel]

    #pragma unroll 4
    for (int ks = 0; ks < 32; ++ks) {          // 4 k's per step
        f32x4 xv[4], wv[4];
        #pragma unroll
        for (int n = 0; n < 4; ++n) xv[n] = xr[n][ks];
        #pragma unroll
        for (int kk = 0; kk < 4; ++kk)
            wv[kk] = *(const f32x4*)&swc[(ks * 4 + kk) * 32 + r0];

        #pragma unroll
        for (int n = 0; n < 4; ++n) {
            #pragma unroll
            for (int c = 0; c < 4; ++c) {
                acc[n][0] += xv[n][c] * wv[c][0];
                acc[n][1] += xv[n][c] * wv[c][1];
                acc[n][2] += xv[n][c] * wv[c][2];
                acc[n][3] += xv[n][c] * wv[c][3];
            }
        }
    }

    // Relation-major store: per rel rr, pack the 4 consecutive nodes -> 8B.
    if (node0 + 3 < num_nodes) {
        #pragma unroll
        for (int rr = 0; rr < 4; ++rr) {
            union { __half2 h2[2]; uint2 u; } pk;
            pk.h2[0] = __floats2half2_rn(acc[0][rr], acc[1][rr]);
            pk.h2[1] = __floats2half2_rn(acc[2][rr], acc[3][rr]);
            *(uint2*)(LR + (size_t)(r0 + rr) * Npad + node0) = pk.u;
        }
    } else {
        #pragma unroll
        for (int rr = 0; rr < 4; ++rr)
            #pragma unroll
            for (int n = 0; n < 4; ++n)
                if (valid[n])
                    LR[(size_t)(r0 + rr) * Npad + node0 + n] = __float2half(acc[n][rr]);
    }
}

// ---------------------------------------------------------------------------
// Kernel 2: phase-locked gather. 8 edges/thread. The r-loop issues each
// edge's gathers during iteration r == t[edge]; all co-resident blocks sweep
// r together, so the chip-wide hot set is ~2 slabs (~200 KB) per phase ->
// L2-resident regardless of replacement policy. Addresses don't depend on r;
// the loop is purely a temporal-locality schedule.
// ---------------------------------------------------------------------------
__global__ __launch_bounds__(256) void edge_score_rm(
    const int* __restrict__ ei,       // (2, E) int32
    const int* __restrict__ et,       // (E,) int32
    const __half* __restrict__ LR,    // (32, Npad)
    int Npad,
    float* __restrict__ out,
    int num_edges)
{
    const int i = blockIdx.x * blockDim.x + threadIdx.x;   // octet index
    if (i * 8 >= num_edges) return;

    const i32x4* es = (const i32x4*)ei;
    const i32x4* ed = (const i32x4*)(ei + num_edges);
    const i32x4* tt = (const i32x4*)et;

    const i32x4 sa = es[2 * i], sb = es[2 * i + 1];
    const i32x4 da = ed[2 * i], db = ed[2 * i + 1];
    const i32x4 ta = tt[2 * i], tb = tt[2 * i + 1];

    int s[8], d[8], t[8];
    #pragma unroll
    for (int j = 0; j < 4; ++j) {
        s[j] = sa[j]; s[4 + j] = sb[j];
        d[j] = da[j]; d[4 + j] = db[j];
        t[j] = ta[j]; t[4 + j] = tb[j];
    }

    __half hs[8], hd[8];
    #pragma unroll
    for (int j = 0; j < 8; ++j) { hs[j] = __half(0.f); hd[j] = __half(0.f); }

    // Phase loop: rolled on purpose (16 iterations).
    #pragma unroll 1
    for (int r = 0; r < NUM_REL; ++r) {
        const __half* slab_s = LR + (size_t)r * Npad;
        const __half* slab_d = LR + (size_t)(NUM_REL + r) * Npad;
        #pragma unroll
        for (int j = 0; j < 8; ++j) {
            if (t[j] == r) {
                hs[j] = slab_s[s[j]];
                hd[j] = slab_d[d[j]];
            }
        }
    }

    f32x4 res[2];
    #pragma unroll
    for (int j = 0; j < 8; ++j) {
        const float sc = __half2float(hs[j]) + __half2float(hd[j]);
        const float att = 1.f / (1.f + __expf(-sc));
        res[j >> 2][j & 3] = fminf(fmaxf(att, 1e-5f), 0.99999f);
    }
    f32x4* o = (f32x4*)out;
    o[2 * i]     = res[0];
    o[2 * i + 1] = res[1];
}

// Fallback: direct per-edge dot product in f32 (no workspace).
__global__ void edge_direct_kernel(const float* __restrict__ x,
                                   const float* __restrict__ w,
                                   const int* __restrict__ ei,
                                   const int* __restrict__ et,
                                   float* __restrict__ out,
                                   int num_edges) {
    const int e = blockIdx.x * blockDim.x + threadIdx.x;
    if (e >= num_edges) return;
    const int s = ei[e];
    const int d = ei[num_edges + e];
    const int t = et[e];
    const float* xs = x + (size_t)s * INPUT_SIZE;
    const float* xd = x + (size_t)d * INPUT_SIZE;
    float acc = 0.f;
    #pragma unroll 4
    for (int k = 0; k < INPUT_SIZE; ++k)
        acc += xs[k] * w[k * NUM_REL + t] + xd[k] * w[(INPUT_SIZE + k) * NUM_REL + t];
    const float att = 1.f / (1.f + __expf(-acc));
    out[e] = fminf(fmaxf(att, 1e-5f), 0.99999f);
}

extern "C" void kernel_launch(void* const* d_in, const int* in_sizes, int n_in,
                              void* d_out, int out_size, void* d_ws, size_t ws_size,
                              hipStream_t stream) {
    const float* x  = (const float*)d_in[0];   // (50000, 128) f32
    const float* w  = (const float*)d_in[1];   // (256, 16) f32
    const int*   ei = (const int*)d_in[2];     // (2, E) int32
    const int*   et = (const int*)d_in[3];     // (E,) int32
    float* out = (float*)d_out;

    const int num_nodes = in_sizes[0] / INPUT_SIZE;
    const int num_edges = in_sizes[3];

    const int Npad = (num_nodes + 63) & ~63;   // 64-node (128B) aligned slabs
    const size_t ws_needed = (size_t)32 * Npad * sizeof(__half);   // ~3.2 MB

    if (ws_size >= ws_needed && (num_edges & 7) == 0) {
        __half* LR = (__half*)d_ws;

        const int blocks1 = (num_nodes + 127) / 128;
        node_logits_rm<<<blocks1, 256, 0, stream>>>(x, w, LR, Npad, num_nodes);

        const int octs    = num_edges / 8;
        const int blocks2 = (octs + 255) / 256;
        edge_score_rm<<<blocks2, 256, 0, stream>>>(ei, et, LR, Npad, out, num_edges);
    } else {
        const int blocks = (num_edges + 255) / 256;
        edge_direct_kernel<<<blocks, 256, 0, stream>>>(x, w, ei, et, out, num_edges);
    }
}